// Round 12
// baseline (358.720 us; speedup 1.0000x reference)
//
#include <hip/hip_runtime.h>
#include <hip/hip_bf16.h>
#include <math.h>

typedef unsigned int u32;
typedef unsigned short u16;
typedef __attribute__((ext_vector_type(8))) short bf8v;   // 8 bf16 = 4 VGPR
typedef __attribute__((ext_vector_type(4))) float f4v;    // 4 f32 acc

#define B_    4
#define N_    131072
#define P_    (B_*N_)          // 524288
#define GX_   512
#define GY_   512
#define S_    (B_*GX_*GY_)     // 1048576
#define D_IN  25
#define MAXPT 64
#define EPS_  1e-5f
#define REP_  32               // stats replica rows (contention /32)

__device__ __forceinline__ float bf2f(u16 h){ return __uint_as_float(((u32)h)<<16); }
__device__ __forceinline__ u16 f2bf(float f){ u32 b=__float_as_uint(f); u32 r=b+0x7FFFu+((b>>16)&1u); return (u16)(r>>16); }
// monotone f32<->u32 encoding; 0u = "empty" sentinel (only NaN maps to 0)
__device__ __forceinline__ u32 encf(float f){ u32 b=__float_as_uint(f); return (b&0x80000000u)? ~b : (b|0x80000000u); }
__device__ __forceinline__ float decf(u32 e){ return __uint_as_float((e&0x80000000u)? (e&0x7FFFFFFFu) : ~e); }

__device__ __forceinline__ void unpack8(uint4 a, float* x){
  x[0]=bf2f((u16)(a.x&0xFFFFu)); x[1]=bf2f((u16)(a.x>>16));
  x[2]=bf2f((u16)(a.y&0xFFFFu)); x[3]=bf2f((u16)(a.y>>16));
  x[4]=bf2f((u16)(a.z&0xFFFFu)); x[5]=bf2f((u16)(a.z>>16));
  x[6]=bf2f((u16)(a.w&0xFFFFu)); x[7]=bf2f((u16)(a.w>>16));
}

// build raw 25-dim feature (padded to 32) for point p
__device__ __forceinline__ void buildFeat(int p, const float* __restrict__ fea,
    const int* __restrict__ lab, const float* __restrict__ emb, float* v)
{
  #pragma unroll
  for (int k=0;k<9;k++) v[k] = fea[p*9+k];
  int l = lab[p];
  const float4* er = (const float4*)(emb + l*16);
  float4 e0=er[0], e1=er[1], e2=er[2], e3=er[3];
  v[9]=e0.x; v[10]=e0.y; v[11]=e0.z; v[12]=e0.w;
  v[13]=e1.x; v[14]=e1.y; v[15]=e1.z; v[16]=e1.w;
  v[17]=e2.x; v[18]=e2.y; v[19]=e2.z; v[20]=e2.w;
  v[21]=e3.x; v[22]=e3.y; v[23]=e3.z; v[24]=e3.w;
  #pragma unroll
  for (int k=25;k<32;k++) v[k]=0.f;
}

// block-wide column-sum/sumsq of 32 per-thread values via LDS transpose tile.
__device__ __forceinline__ void stats32(float* tile, float* sS, float* sQ,
                                        const float v[32], int tid)
{
  #pragma unroll
  for (int k=0;k<32;k++) tile[tid*33+k] = v[k];
  __syncthreads();
  int c = tid & 31, g = tid >> 5;
  float s=0.f, q=0.f;
  #pragma unroll
  for (int r=0;r<32;r++){
    float x = tile[(g*32+r)*33 + c];
    s += x; q = fmaf(x,x,q);
  }
  atomicAdd(&sS[c], s); atomicAdd(&sQ[c], q);
  __syncthreads();
}

// ---------------- zeroK ------------------------------------------------------
__global__ __launch_bounds__(256) void zeroK(u32* __restrict__ cnt, float* __restrict__ stats)
{
  int t = blockIdx.x*256 + threadIdx.x;
  ((uint4*)cnt)[t] = make_uint4(0,0,0,0);
  if (blockIdx.x == 0){
    #pragma unroll
    for (int k=0;k<8;k++)
      ((uint4*)stats)[threadIdx.x*8+k] = make_uint4(0,0,0,0);
  }
}

// ---------------- pass A: voxel rank/flags + bn0 partial stats ---------------
__global__ __launch_bounds__(256) void passA(
    const float* __restrict__ fea, const int* __restrict__ xy, const int* __restrict__ lab,
    const float* __restrict__ emb, u32* __restrict__ cnt, u32* __restrict__ voxflag,
    float* __restrict__ partA)
{
  __shared__ float tile[256*33];
  __shared__ float sS[32], sQ[32];
  int tid = threadIdx.x;
  if (tid < 32){ sS[tid]=0.f; sQ[tid]=0.f; }
  int p = blockIdx.x*256 + tid;
  int b = p >> 17;
  int ix = xy[2*p], iy = xy[2*p+1];
  u32 vox = ((u32)b<<18) + ((u32)ix<<9) + (u32)iy;
  u32 rank = atomicAdd(&cnt[vox], 1u);
  bool remain = rank < MAXPT;
  voxflag[p] = vox | (min(rank,63u)<<20) | (remain ? 0x80000000u : 0u);

  float v[32];
  buildFeat(p, fea, lab, emb, v);
  if (!remain){
    #pragma unroll
    for (int k=0;k<32;k++) v[k]=0.f;
  }
  __syncthreads();
  stats32(tile, sS, sQ, v, tid);
  int rep = blockIdx.x & (REP_-1);
  if (tid < 32) atomicAdd(&partA[rep*64+tid], sS[tid]);
  else if (tid < 64) atomicAdd(&partA[rep*64+tid], sQ[tid-32]);
}

// ---------------- scans ------------------------------------------------------
__global__ __launch_bounds__(256) void scan1(const u32* __restrict__ cnt,
                                             u32* __restrict__ scanned, u32* __restrict__ blockSum)
{
  __shared__ u32 ts[256];
  int tid = threadIdx.x;
  size_t base = (size_t)blockIdx.x*1024 + tid*4;
  uint4 c4 = *(const uint4*)(cnt + base);
  u32 c0=min(c4.x,64u), c1=min(c4.y,64u), c2=min(c4.z,64u), c3=min(c4.w,64u);
  u32 tsum = c0+c1+c2+c3;
  ts[tid]=tsum; __syncthreads();
  for (int off=1; off<256; off<<=1){
    u32 v = (tid>=off)? ts[tid-off] : 0u; __syncthreads();
    ts[tid]+=v; __syncthreads();
  }
  u32 ex = ts[tid]-tsum;
  uint4 o; o.x=ex; o.y=ex+c0; o.z=ex+c0+c1; o.w=ex+c0+c1+c2;
  *(uint4*)(scanned+base)=o;
  if (tid==255) blockSum[blockIdx.x]=ts[255];
}

__global__ __launch_bounds__(256) void scan2p0(u32* __restrict__ bs, u32* __restrict__ cntW,
    const float* __restrict__ partA,
    const float* __restrict__ g0, const float* __restrict__ b0,
    const float* __restrict__ w1, const float* __restrict__ b1,
    float* __restrict__ W1T, float* __restrict__ c1f)
{
  __shared__ u32 ts[256];
  __shared__ float red[64];
  __shared__ float s0[32], t0[32];
  __shared__ float Wsh;
  int tid=threadIdx.x;
  uint4 c4 = *(uint4*)(bs + tid*4);
  u32 tsum=c4.x+c4.y+c4.z+c4.w;
  ts[tid]=tsum; __syncthreads();
  for (int off=1;off<256;off<<=1){ u32 v=(tid>=off)?ts[tid-off]:0u; __syncthreads(); ts[tid]+=v; __syncthreads(); }
  u32 ex=ts[tid]-tsum;
  uint4 o; o.x=ex; o.y=ex+c4.x; o.z=ex+c4.x+c4.y; o.w=ex+c4.x+c4.y+c4.z;
  *(uint4*)(bs+tid*4)=o;
  if (tid==255){ *cntW = ts[255]; Wsh = fmaxf((float)ts[255],1.f); }
  if (tid < 64){
    float acc=0.f;
    for (int r=0;r<REP_;r++) acc += partA[r*64+tid];
    red[tid]=acc;
  }
  __syncthreads();
  if (tid < D_IN){
    float W = Wsh;
    float mu = red[tid]/W;
    float var = fmaxf(red[32+tid]/W - mu*mu, 0.f);
    float s = g0[tid]*rsqrtf(var+EPS_);
    s0[tid]=s; t0[tid]=b0[tid]-mu*s;
  }
  __syncthreads();
  if (tid < 32){
    float acc = b1[tid];
    #pragma unroll
    for (int i=0;i<D_IN;i++) acc = fmaf(t0[i], w1[i*32+tid], acc);
    c1f[tid] = acc;
    for (int i=0;i<32;i++) W1T[tid*32+i] = (i<D_IN)? s0[i]*w1[i*32+tid] : 0.f;
  }
}

// ---------------- scatterK: point index list per voxel segment ---------------
__global__ __launch_bounds__(256) void scatterK(const u32* __restrict__ voxflag,
    const u32* __restrict__ scanned, const u32* __restrict__ bsum, u32* __restrict__ sortedIdx)
{
  int p = blockIdx.x*256+threadIdx.x;
  u32 vf = voxflag[p];
  if (vf>>31){
    u32 vox = vf & 0xFFFFFu;
    u32 rank = (vf>>20)&63u;
    sortedIdx[scanned[vox] + bsum[vox>>10] + rank] = (u32)p;
  }
}

// ---------------- param kernels (affines only; raw w2/w3 used by MFMA) -------
__global__ void p1k(const float* __restrict__ partB, const u32* __restrict__ cntW,
                    const float* __restrict__ g, const float* __restrict__ bb,
                    float* __restrict__ sOut, float* __restrict__ tOut)
{
  int tid = threadIdx.x; // 32
  float s=0.f, q=0.f;
  for (int r=0;r<REP_;r++){ s += partB[r*64+tid]; q += partB[r*64+32+tid]; }
  float W = fmaxf((float)(*cntW),1.f);
  float mu = s/W, var = fmaxf(q/W-mu*mu,0.f);
  float sc = g[tid]*rsqrtf(var+EPS_);
  sOut[tid]=sc; tOut[tid]=bb[tid]-mu*sc;
}
__global__ void p2k(const float* __restrict__ partC, const u32* __restrict__ cntW,
                    const float* __restrict__ g, const float* __restrict__ bb,
                    float* __restrict__ sOut, float* __restrict__ tOut)
{
  __shared__ float red[128];
  int tid = threadIdx.x; // 128
  float acc=0.f;
  for (int r=0;r<REP_;r++) acc += partC[r*128+tid];
  red[tid]=acc;
  __syncthreads();
  if (tid < 64){
    float W = fmaxf((float)(*cntW),1.f);
    float mu = red[tid]/W, var = fmaxf(red[64+tid]/W-mu*mu,0.f);
    float s = g[tid]*rsqrtf(var+EPS_);
    sOut[tid]=s; tOut[tid]=bb[tid]-mu*s;
  }
}

// ---------------- pass B: rebuild feat, y1 = x@W1T + c1f, + bn1 partials -----
__global__ __launch_bounds__(256) void passB(
    const float* __restrict__ fea, const int* __restrict__ lab, const float* __restrict__ emb,
    const u32* __restrict__ voxflag,
    const float* __restrict__ W1T, const float* __restrict__ c1f,
    u16* __restrict__ y1, float* __restrict__ partB)
{
  __shared__ float tile[256*33];
  __shared__ float sS[32], sQ[32];
  int tid = threadIdx.x;
  if (tid < 32){ sS[tid]=0.f; sQ[tid]=0.f; }
  int p = blockIdx.x*256 + tid;
  float x[32];
  buildFeat(p, fea, lab, emb, x);
  bool flag = (voxflag[p]>>31) != 0;
  float a[32];
  u32 outp[16];
  #pragma unroll
  for (int cc=0; cc<16; cc++){
    int c0 = 2*cc;
    float a0=c1f[c0], a1=c1f[c0+1];
    #pragma unroll
    for (int i=0;i<32;i++){ a0=fmaf(x[i], W1T[c0*32+i], a0); a1=fmaf(x[i], W1T[(c0+1)*32+i], a1); }
    if(!flag){a0=0.f;a1=0.f;}
    a[c0]=a0; a[c0+1]=a1;
    outp[cc] = (u32)f2bf(a0) | ((u32)f2bf(a1)<<16);
  }
  uint4* dst = (uint4*)(y1 + (size_t)p*32);
  dst[0]=make_uint4(outp[0],outp[1],outp[2],outp[3]);
  dst[1]=make_uint4(outp[4],outp[5],outp[6],outp[7]);
  dst[2]=make_uint4(outp[8],outp[9],outp[10],outp[11]);
  dst[3]=make_uint4(outp[12],outp[13],outp[14],outp[15]);
  __syncthreads();
  stats32(tile, sS, sQ, a, tid);
  int rep = blockIdx.x & (REP_-1);
  if (tid < 32) atomicAdd(&partB[rep*64+tid], sS[tid]);
  else if (tid < 64) atomicAdd(&partB[rep*64+tid], sQ[tid-32]);
}

// ---------------- passCM: MFMA y2 = relu(bn1(y1)) @ w2 + b2, + bn2 partials --
__global__ __launch_bounds__(256) void passCM(const u16* __restrict__ y1,
    const u32* __restrict__ voxflag,
    const float* __restrict__ s1, const float* __restrict__ t1,
    const float* __restrict__ w2, const float* __restrict__ b2,
    u16* __restrict__ y2, float* __restrict__ partC)
{
  __shared__ u16 zt4[4][16*72];
  __shared__ float s1s[32], t1s[32];
  __shared__ float sS[64], sQ[64];
  int tid = threadIdx.x;
  if (tid < 32){ s1s[tid]=s1[tid]; t1s[tid]=t1[tid]; }
  if (tid < 64){ sS[tid]=0.f; sQ[tid]=0.f; }
  __syncthreads();
  int wv = tid>>6, l = tid&63;
  int p0 = blockIdx.x*64 + wv*16;
  int m = l&15, kc = l>>4;
  u16* zt = zt4[wv];

  bf8v Bf[4];
  #pragma unroll
  for (int nt=0;nt<4;nt++){
    #pragma unroll
    for (int j=0;j<8;j++)
      Bf[nt][j] = (short)f2bf(w2[(kc*8+j)*64 + nt*16 + m]);
  }
  uint4 ra = *(const uint4*)(y1 + (size_t)(p0+m)*32 + kc*8);
  float xv[8]; unpack8(ra, xv);
  bf8v Af;
  #pragma unroll
  for (int j=0;j<8;j++){
    int ch = kc*8+j;
    Af[j] = (short)f2bf(fmaxf(fmaf(xv[j], s1s[ch], t1s[ch]), 0.f));
  }
  unsigned long long msk = __ballot((l<16) && ((voxflag[p0+l]>>31)!=0));

  f4v acc[4];
  #pragma unroll
  for (int nt=0;nt<4;nt++){
    float bb = b2[nt*16+m];
    acc[nt] = (f4v){bb,bb,bb,bb};
    acc[nt] = __builtin_amdgcn_mfma_f32_16x16x32_bf16(Af, Bf[nt], acc[nt], 0,0,0);
  }
  #pragma unroll
  for (int nt=0;nt<4;nt++){
    #pragma unroll
    for (int r=0;r<4;r++){
      int row = kc*4+r;
      u16 val = ((msk>>row)&1ull) ? f2bf(acc[nt][r]) : (u16)0;
      zt[row*72 + nt*16+m] = val;
    }
  }
  __syncthreads();
  {
    float s=0.f, q=0.f;
    #pragma unroll
    for (int mi=0;mi<16;mi++){ float v = bf2f(zt[mi*72 + l]); s+=v; q=fmaf(v,v,q); }
    atomicAdd(&sS[l], s); atomicAdd(&sQ[l], q);
  }
  {
    int mm = l>>2, q4 = l&3;
    const uint4* src = (const uint4*)(zt + mm*72 + q4*16);
    uint4 v0 = src[0], v1 = src[1];
    uint4* dy = (uint4*)(y2 + (size_t)(p0+mm)*64 + q4*16);
    dy[0]=v0; dy[1]=v1;
  }
  __syncthreads();
  int rep = blockIdx.x & (REP_-1);
  if (tid < 64) atomicAdd(&partC[rep*128+tid], sS[tid]);
  else if (tid < 128) atomicAdd(&partC[rep*128+tid], sQ[tid-64]);
}

// ---------------- zpoolM: fused MFMA final layer + segment pool + transpose --
// block = 128 voxels (contiguous slots); loops 64-slot MFMA tiles; pools via
// run-length max + LDS atomicMax into pm[vl*66+c] (2 lanes/bank = free);
// writes pooledT[b][c][ix][iy] with 64B runs per thread.
#define PVOX 128
__global__ __launch_bounds__(256) void zpoolM(
    const u32* __restrict__ sortedIdx, const u32* __restrict__ scanned,
    const u32* __restrict__ bsum, const u32* __restrict__ cntW,
    const u16* __restrict__ y2, const u32* __restrict__ voxflag,
    const float* __restrict__ s2, const float* __restrict__ t2,
    const float* __restrict__ w3, const float* __restrict__ b3,
    u16* __restrict__ pooledT)
{
  __shared__ u32 pm[PVOX*66];        // 33.8 KB, enc-f32, 0 = empty
  __shared__ u16 zt4[4][16*72];      // 9.2 KB
  __shared__ unsigned char vl[64];
  __shared__ float s2s[64], t2s[64];
  int tid = threadIdx.x;
  int v0 = blockIdx.x*PVOX;
  if (tid < 64){ s2s[tid]=s2[tid]; t2s[tid]=t2[tid]; }
  for (int k=tid;k<PVOX*66;k+=256) pm[k]=0u;
  u32 sBeg = scanned[v0] + bsum[v0>>10];
  int vend = v0 + PVOX;
  u32 sEnd = (vend == S_) ? *cntW : (scanned[vend] + bsum[vend>>10]);
  int wv = tid>>6, l = tid&63;
  int m = l&15, kc = l>>4;

  bf8v Bf[4][2];
  #pragma unroll
  for (int nt=0;nt<4;nt++){
    #pragma unroll
    for (int kt=0;kt<2;kt++){
      #pragma unroll
      for (int j=0;j<8;j++)
        Bf[nt][kt][j] = (short)f2bf(w3[(kc*8+j+32*kt)*64 + nt*16 + m]);
    }
  }
  __syncthreads();

  int ntile = (int)((sEnd - sBeg + 63u)>>6);
  for (int t5=0; t5<ntile; ++t5){
    u32 slot = sBeg + (u32)t5*64u + (u32)(wv*16+m);
    bool valid = slot < sEnd;
    u32 p = valid ? sortedIdx[slot] : 0u;
    if (kc==0)
      vl[wv*16+m] = valid ? (unsigned char)((voxflag[p]&0xFFFFFu) - (u32)v0) : (unsigned char)255;
    uint4 r0 = *(const uint4*)(y2 + (size_t)p*64 + kc*8);
    uint4 r1 = *(const uint4*)(y2 + (size_t)p*64 + 32 + kc*8);
    float x0[8], x1[8]; unpack8(r0,x0); unpack8(r1,x1);
    bf8v A0, A1;
    #pragma unroll
    for (int j=0;j<8;j++){
      int c0 = kc*8+j, c1 = 32+kc*8+j;
      A0[j] = (short)f2bf(fmaxf(fmaf(x0[j], s2s[c0], t2s[c0]), 0.f));
      A1[j] = (short)f2bf(fmaxf(fmaf(x1[j], s2s[c1], t2s[c1]), 0.f));
    }
    f4v acc[4];
    #pragma unroll
    for (int nt=0;nt<4;nt++){
      float bb = b3[nt*16+m];
      acc[nt] = (f4v){bb,bb,bb,bb};
      acc[nt] = __builtin_amdgcn_mfma_f32_16x16x32_bf16(A0, Bf[nt][0], acc[nt], 0,0,0);
      acc[nt] = __builtin_amdgcn_mfma_f32_16x16x32_bf16(A1, Bf[nt][1], acc[nt], 0,0,0);
    }
    u16* zt = zt4[wv];
    #pragma unroll
    for (int nt=0;nt<4;nt++){
      #pragma unroll
      for (int r=0;r<4;r++)
        zt[(kc*4+r)*72 + nt*16+m] = f2bf(acc[nt][r]);
    }
    __syncthreads();
    // pool this tile: thread = (channel c, row-group rg of 16)
    {
      int c = tid & 63, rg = tid>>6;
      float mx = 0.f; int curv = -1;
      for (int rr=rg*16; rr<rg*16+16; ++rr){
        int vv = vl[rr];
        if (vv==255) continue;
        float zz = bf2f(zt4[rr>>4][(rr&15)*72 + c]);
        if (vv != curv){
          if (curv>=0) atomicMax(&pm[curv*66+c], encf(mx));
          curv = vv; mx = zz;
        } else {
          mx = fmaxf(mx, zz);
        }
      }
      if (curv>=0) atomicMax(&pm[curv*66+c], encf(mx));
    }
    __syncthreads();
  }

  // write-out: thread = (c = tid&63, seg = tid>>6 of 32 voxels) -> 64B run
  {
    int c = tid&63, seg = tid>>6;
    int iy0 = (v0 & 511) + seg*32;
    int ix = (v0>>9)&511, b = v0>>18;
    u16 ob[32];
    #pragma unroll
    for (int j=0;j<32;j++){
      u32 e = pm[(seg*32+j)*66 + c];
      ob[j] = (e==0u) ? (u16)0 : f2bf(decf(e));
    }
    u16* dst = pooledT + (((size_t)(b*64+c)*512 + ix)*512 + iy0);
    #pragma unroll
    for (int q=0;q<4;q++) ((uint4*)dst)[q] = ((uint4*)ob)[q];
  }
}

// ---------------- dilate: per-(b,c)-plane streaming 3x3 max ------------------
#define ITILE 32
__global__ __launch_bounds__(256) void dilate(const u16* __restrict__ pooledT, float* __restrict__ out)
{
  __shared__ float sh[2][516];
  int it = blockIdx.x;
  int c  = blockIdx.y;
  int b  = blockIdx.z;
  int tid = threadIdx.x;
  int j0 = tid*2;
  const u16* plane = pooledT + ((size_t)(b*64+c)*512)*512;
  float* oplane = out + ((size_t)(b*64+c)*512)*512;
  const float NINF = -__builtin_inff();
  if (tid==0){ sh[0][0]=NINF; sh[1][0]=NINF; }
  if (tid==255){ sh[0][513]=NINF; sh[1][513]=NINF; }
  int i0 = it*ITILE;

  float a0x,a0y,a1x,a1y,a2x,a2y;
  {
    int r = i0-1;
    if (r<0){ a0x=NINF; a0y=NINF; }
    else { u32 w=*(const u32*)(plane+(size_t)r*512+j0); a0x=bf2f((u16)(w&0xFFFFu)); a0y=bf2f((u16)(w>>16)); }
  }
  {
    u32 w=*(const u32*)(plane+(size_t)i0*512+j0); a1x=bf2f((u16)(w&0xFFFFu)); a1y=bf2f((u16)(w>>16));
  }
  for (int i=i0; i<i0+ITILE; i++){
    int r = i+1;
    if (r>511){ a2x=NINF; a2y=NINF; }
    else { u32 w=*(const u32*)(plane+(size_t)r*512+j0); a2x=bf2f((u16)(w&0xFFFFu)); a2y=bf2f((u16)(w>>16)); }
    int buf = i&1;
    sh[buf][1+j0] = fmaxf(fmaxf(a0x,a1x),a2x);
    sh[buf][2+j0] = fmaxf(fmaxf(a0y,a1y),a2y);
    __syncthreads();
    float s0=sh[buf][j0], s1=sh[buf][j0+1], s2=sh[buf][j0+2], s3=sh[buf][j0+3];
    float2 o = make_float2(fmaxf(fmaxf(s0,s1),s2), fmaxf(fmaxf(s1,s2),s3));
    *(float2*)(oplane + (size_t)i*512 + j0) = o;
    a0x=a1x; a0y=a1y; a1x=a2x; a1y=a2y;
  }
}

// -----------------------------------------------------------------------------
extern "C" void kernel_launch(void* const* d_in, const int* in_sizes, int n_in,
                              void* d_out, int out_size, void* d_ws, size_t ws_size,
                              hipStream_t stream) {
  const float* fea  = (const float*)d_in[0];
  const int*   xy   = (const int*)d_in[1];
  const int*   lab  = (const int*)d_in[2];
  const float* emb  = (const float*)d_in[3];
  const float* bn0g = (const float*)d_in[4];
  const float* bn0b = (const float*)d_in[5];
  const float* w1   = (const float*)d_in[6];
  const float* b1   = (const float*)d_in[7];
  const float* bn1g = (const float*)d_in[8];
  const float* bn1b = (const float*)d_in[9];
  const float* w2   = (const float*)d_in[10];
  const float* b2   = (const float*)d_in[11];
  const float* bn2g = (const float*)d_in[12];
  const float* bn2b = (const float*)d_in[13];
  const float* w3   = (const float*)d_in[14];
  const float* b3   = (const float*)d_in[15];

  char* ws = (char*)d_ws;
  size_t off = 0;
  u16*  pooledT = (u16*)(ws + off); off += (size_t)S_*64*2;   // 134.2 MB transposed
  u32*  cnt     = (u32*)(ws + off); off += (size_t)S_*4;
  u32*  scanned = (u32*)(ws + off); off += (size_t)S_*4;
  u32*  voxflag = (u32*)(ws + off); off += (size_t)P_*4;
  u32*  sortedIdx=(u32*)(ws + off); off += (size_t)P_*4;
  u32*  blockSum= (u32*)(ws + off); off += 4096;
  float* stats  = (float*)(ws + off);
  float* partA = stats + 0;
  float* partB = stats + 2048;
  float* partC = stats + 4096;
  u32*  cntW = (u32*)(stats + 8192);
  float* c1f = stats + 8256;
  float* s1  = stats + 8288;
  float* t1  = stats + 8320;
  float* s2  = stats + 8352;
  float* t2  = stats + 8416;
  float* W1T = stats + 8480;      // 1024

  u16* y1 = (u16*)d_out;                                  // P*32 bf16
  u16* y2 = (u16*)((char*)d_out + (size_t)P_*32*2);       // P*64 bf16
  float* out = (float*)d_out;

  zeroK<<<S_/1024, 256, 0, stream>>>(cnt, stats);
  passA<<<P_/256, 256, 0, stream>>>(fea, xy, lab, emb, cnt, voxflag, partA);
  scan1<<<S_/1024, 256, 0, stream>>>(cnt, scanned, blockSum);
  scan2p0<<<1, 256, 0, stream>>>(blockSum, cntW, partA, bn0g, bn0b, w1, b1, W1T, c1f);
  scatterK<<<P_/256, 256, 0, stream>>>(voxflag, scanned, blockSum, sortedIdx);
  passB<<<P_/256, 256, 0, stream>>>(fea, lab, emb, voxflag, W1T, c1f, y1, partB);
  p1k<<<1, 32, 0, stream>>>(partB, cntW, bn1g, bn1b, s1, t1);
  passCM<<<P_/64, 256, 0, stream>>>(y1, voxflag, s1, t1, w2, b2, y2, partC);
  p2k<<<1, 128, 0, stream>>>(partC, cntW, bn2g, bn2b, s2, t2);
  zpoolM<<<S_/PVOX, 256, 0, stream>>>(sortedIdx, scanned, blockSum, cntW,
                                      y2, voxflag, s2, t2, w3, b3, pooledT);
  dim3 dg(GX_/ITILE, 64, B_);
  dilate<<<dg, 256, 0, stream>>>(pooledT, out);
}

// Round 15
// 333.967 us; speedup vs baseline: 1.0741x; 1.0741x over previous
//
#include <hip/hip_runtime.h>
#include <hip/hip_bf16.h>
#include <math.h>

typedef unsigned int u32;
typedef unsigned short u16;
typedef __attribute__((ext_vector_type(8))) short bf8v;   // 8 bf16 = 4 VGPR
typedef __attribute__((ext_vector_type(4))) float f4v;    // 4 f32 acc

#define B_    4
#define N_    131072
#define P_    (B_*N_)          // 524288
#define GX_   512
#define GY_   512
#define S_    (B_*GX_*GY_)     // 1048576
#define D_IN  25
#define MAXPT 64
#define EPS_  1e-5f
#define REP_  32               // stats replica rows (contention /32)

__device__ __forceinline__ float bf2f(u16 h){ return __uint_as_float(((u32)h)<<16); }
__device__ __forceinline__ u16 f2bf(float f){ u32 b=__float_as_uint(f); u32 r=b+0x7FFFu+((b>>16)&1u); return (u16)(r>>16); }

__device__ __forceinline__ void unpack8(uint4 a, float* x){
  x[0]=bf2f((u16)(a.x&0xFFFFu)); x[1]=bf2f((u16)(a.x>>16));
  x[2]=bf2f((u16)(a.y&0xFFFFu)); x[3]=bf2f((u16)(a.y>>16));
  x[4]=bf2f((u16)(a.z&0xFFFFu)); x[5]=bf2f((u16)(a.z>>16));
  x[6]=bf2f((u16)(a.w&0xFFFFu)); x[7]=bf2f((u16)(a.w>>16));
}

// build raw 25-dim feature (padded to 32) for point p
__device__ __forceinline__ void buildFeat(int p, const float* __restrict__ fea,
    const int* __restrict__ lab, const float* __restrict__ emb, float* v)
{
  #pragma unroll
  for (int k=0;k<9;k++) v[k] = fea[p*9+k];
  int l = lab[p];
  const float4* er = (const float4*)(emb + l*16);
  float4 e0=er[0], e1=er[1], e2=er[2], e3=er[3];
  v[9]=e0.x; v[10]=e0.y; v[11]=e0.z; v[12]=e0.w;
  v[13]=e1.x; v[14]=e1.y; v[15]=e1.z; v[16]=e1.w;
  v[17]=e2.x; v[18]=e2.y; v[19]=e2.z; v[20]=e2.w;
  v[21]=e3.x; v[22]=e3.y; v[23]=e3.z; v[24]=e3.w;
  #pragma unroll
  for (int k=25;k<32;k++) v[k]=0.f;
}

// block-wide column-sum/sumsq of 32 per-thread values via LDS transpose tile.
__device__ __forceinline__ void stats32(float* tile, float* sS, float* sQ,
                                        const float v[32], int tid)
{
  #pragma unroll
  for (int k=0;k<32;k++) tile[tid*33+k] = v[k];
  __syncthreads();
  int c = tid & 31, g = tid >> 5;
  float s=0.f, q=0.f;
  #pragma unroll
  for (int r=0;r<32;r++){
    float x = tile[(g*32+r)*33 + c];
    s += x; q = fmaf(x,x,q);
  }
  atomicAdd(&sS[c], s); atomicAdd(&sQ[c], q);
  __syncthreads();
}

// ---------------- zeroK ------------------------------------------------------
__global__ __launch_bounds__(256) void zeroK(u32* __restrict__ cnt, float* __restrict__ stats)
{
  int t = blockIdx.x*256 + threadIdx.x;
  ((uint4*)cnt)[t] = make_uint4(0,0,0,0);
  if (blockIdx.x == 0){
    #pragma unroll
    for (int k=0;k<8;k++)
      ((uint4*)stats)[threadIdx.x*8+k] = make_uint4(0,0,0,0);
  }
}

// ---------------- pass A: voxel rank/flags + bn0 partial stats ---------------
__global__ __launch_bounds__(256) void passA(
    const float* __restrict__ fea, const int* __restrict__ xy, const int* __restrict__ lab,
    const float* __restrict__ emb, u32* __restrict__ cnt, u32* __restrict__ voxflag,
    float* __restrict__ partA)
{
  __shared__ float tile[256*33];
  __shared__ float sS[32], sQ[32];
  int tid = threadIdx.x;
  if (tid < 32){ sS[tid]=0.f; sQ[tid]=0.f; }
  int p = blockIdx.x*256 + tid;
  int b = p >> 17;
  int ix = xy[2*p], iy = xy[2*p+1];
  u32 vox = ((u32)b<<18) + ((u32)ix<<9) + (u32)iy;
  u32 rank = atomicAdd(&cnt[vox], 1u);
  bool remain = rank < MAXPT;
  voxflag[p] = vox | (min(rank,63u)<<20) | (remain ? 0x80000000u : 0u);

  float v[32];
  buildFeat(p, fea, lab, emb, v);
  if (!remain){
    #pragma unroll
    for (int k=0;k<32;k++) v[k]=0.f;
  }
  __syncthreads();
  stats32(tile, sS, sQ, v, tid);
  int rep = blockIdx.x & (REP_-1);
  if (tid < 32) atomicAdd(&partA[rep*64+tid], sS[tid]);
  else if (tid < 64) atomicAdd(&partA[rep*64+tid], sQ[tid-32]);
}

// ---------------- scans ------------------------------------------------------
__global__ __launch_bounds__(256) void scan1(const u32* __restrict__ cnt,
                                             u32* __restrict__ scanned, u32* __restrict__ blockSum)
{
  __shared__ u32 ts[256];
  int tid = threadIdx.x;
  size_t base = (size_t)blockIdx.x*1024 + tid*4;
  uint4 c4 = *(const uint4*)(cnt + base);
  u32 c0=min(c4.x,64u), c1=min(c4.y,64u), c2=min(c4.z,64u), c3=min(c4.w,64u);
  u32 tsum = c0+c1+c2+c3;
  ts[tid]=tsum; __syncthreads();
  for (int off=1; off<256; off<<=1){
    u32 v = (tid>=off)? ts[tid-off] : 0u; __syncthreads();
    ts[tid]+=v; __syncthreads();
  }
  u32 ex = ts[tid]-tsum;
  uint4 o; o.x=ex; o.y=ex+c0; o.z=ex+c0+c1; o.w=ex+c0+c1+c2;
  *(uint4*)(scanned+base)=o;
  if (tid==255) blockSum[blockIdx.x]=ts[255];
}

__global__ __launch_bounds__(256) void scan2p0(u32* __restrict__ bs, u32* __restrict__ cntW,
    const float* __restrict__ partA,
    const float* __restrict__ g0, const float* __restrict__ b0,
    const float* __restrict__ w1, const float* __restrict__ b1,
    float* __restrict__ W1T, float* __restrict__ c1f)
{
  __shared__ u32 ts[256];
  __shared__ float red[64];
  __shared__ float s0[32], t0[32];
  __shared__ float Wsh;
  int tid=threadIdx.x;
  uint4 c4 = *(uint4*)(bs + tid*4);
  u32 tsum=c4.x+c4.y+c4.z+c4.w;
  ts[tid]=tsum; __syncthreads();
  for (int off=1;off<256;off<<=1){ u32 v=(tid>=off)?ts[tid-off]:0u; __syncthreads(); ts[tid]+=v; __syncthreads(); }
  u32 ex=ts[tid]-tsum;
  uint4 o; o.x=ex; o.y=ex+c4.x; o.z=ex+c4.x+c4.y; o.w=ex+c4.x+c4.y+c4.z;
  *(uint4*)(bs+tid*4)=o;
  if (tid==255){ *cntW = ts[255]; Wsh = fmaxf((float)ts[255],1.f); }
  if (tid < 64){
    float acc=0.f;
    for (int r=0;r<REP_;r++) acc += partA[r*64+tid];
    red[tid]=acc;
  }
  __syncthreads();
  if (tid < D_IN){
    float W = Wsh;
    float mu = red[tid]/W;
    float var = fmaxf(red[32+tid]/W - mu*mu, 0.f);
    float s = g0[tid]*rsqrtf(var+EPS_);
    s0[tid]=s; t0[tid]=b0[tid]-mu*s;
  }
  __syncthreads();
  if (tid < 32){
    float acc = b1[tid];
    #pragma unroll
    for (int i=0;i<D_IN;i++) acc = fmaf(t0[i], w1[i*32+tid], acc);
    c1f[tid] = acc;
    for (int i=0;i<32;i++) W1T[tid*32+i] = (i<D_IN)? s0[i]*w1[i*32+tid] : 0.f;
  }
}

// ---------------- param kernels (affines only; raw w2/w3 used by MFMA) -------
__global__ void p1k(const float* __restrict__ partB, const u32* __restrict__ cntW,
                    const float* __restrict__ g, const float* __restrict__ bb,
                    float* __restrict__ sOut, float* __restrict__ tOut)
{
  int tid = threadIdx.x; // 32
  float s=0.f, q=0.f;
  for (int r=0;r<REP_;r++){ s += partB[r*64+tid]; q += partB[r*64+32+tid]; }
  float W = fmaxf((float)(*cntW),1.f);
  float mu = s/W, var = fmaxf(q/W-mu*mu,0.f);
  float sc = g[tid]*rsqrtf(var+EPS_);
  sOut[tid]=sc; tOut[tid]=bb[tid]-mu*sc;
}
__global__ void p2k(const float* __restrict__ partC, const u32* __restrict__ cntW,
                    const float* __restrict__ g, const float* __restrict__ bb,
                    float* __restrict__ sOut, float* __restrict__ tOut)
{
  __shared__ float red[128];
  int tid = threadIdx.x; // 128
  float acc=0.f;
  for (int r=0;r<REP_;r++) acc += partC[r*128+tid];
  red[tid]=acc;
  __syncthreads();
  if (tid < 64){
    float W = fmaxf((float)(*cntW),1.f);
    float mu = red[tid]/W, var = fmaxf(red[64+tid]/W-mu*mu,0.f);
    float s = g[tid]*rsqrtf(var+EPS_);
    sOut[tid]=s; tOut[tid]=bb[tid]-mu*s;
  }
}

// ---------------- pass B: rebuild feat, y1 = x@W1T + c1f, + bn1 partials -----
__global__ __launch_bounds__(256) void passB(
    const float* __restrict__ fea, const int* __restrict__ lab, const float* __restrict__ emb,
    const u32* __restrict__ voxflag,
    const float* __restrict__ W1T, const float* __restrict__ c1f,
    u16* __restrict__ y1, float* __restrict__ partB)
{
  __shared__ float tile[256*33];
  __shared__ float sS[32], sQ[32];
  int tid = threadIdx.x;
  if (tid < 32){ sS[tid]=0.f; sQ[tid]=0.f; }
  int p = blockIdx.x*256 + tid;
  float x[32];
  buildFeat(p, fea, lab, emb, x);
  bool flag = (voxflag[p]>>31) != 0;
  float a[32];
  u32 outp[16];
  #pragma unroll
  for (int cc=0; cc<16; cc++){
    int c0 = 2*cc;
    float a0=c1f[c0], a1=c1f[c0+1];
    #pragma unroll
    for (int i=0;i<32;i++){ a0=fmaf(x[i], W1T[c0*32+i], a0); a1=fmaf(x[i], W1T[(c0+1)*32+i], a1); }
    if(!flag){a0=0.f;a1=0.f;}
    a[c0]=a0; a[c0+1]=a1;
    outp[cc] = (u32)f2bf(a0) | ((u32)f2bf(a1)<<16);
  }
  uint4* dst = (uint4*)(y1 + (size_t)p*32);
  dst[0]=make_uint4(outp[0],outp[1],outp[2],outp[3]);
  dst[1]=make_uint4(outp[4],outp[5],outp[6],outp[7]);
  dst[2]=make_uint4(outp[8],outp[9],outp[10],outp[11]);
  dst[3]=make_uint4(outp[12],outp[13],outp[14],outp[15]);
  __syncthreads();
  stats32(tile, sS, sQ, a, tid);
  int rep = blockIdx.x & (REP_-1);
  if (tid < 32) atomicAdd(&partB[rep*64+tid], sS[tid]);
  else if (tid < 64) atomicAdd(&partB[rep*64+tid], sQ[tid-32]);
}

// ---------------- passCM: MFMA y2 = relu(bn1(y1)) @ w2 + b2, + bn2 partials --
// wave = 16-point tile. A: lane row=l&15, k=(l>>4)*8+j. B from raw w2[32][64].
// D: col=lane&15, row=(lane>>4)*4+reg (verified map). LDS tile pitch 72 u16.
__global__ __launch_bounds__(256) void passCM(const u16* __restrict__ y1,
    const u32* __restrict__ voxflag,
    const float* __restrict__ s1, const float* __restrict__ t1,
    const float* __restrict__ w2, const float* __restrict__ b2,
    u16* __restrict__ y2, float* __restrict__ partC)
{
  __shared__ u16 zt4[4][16*72];
  __shared__ float s1s[32], t1s[32];
  __shared__ float sS[64], sQ[64];
  int tid = threadIdx.x;
  if (tid < 32){ s1s[tid]=s1[tid]; t1s[tid]=t1[tid]; }
  if (tid < 64){ sS[tid]=0.f; sQ[tid]=0.f; }
  __syncthreads();
  int wv = tid>>6, l = tid&63;
  int p0 = blockIdx.x*64 + wv*16;
  int m = l&15, kc = l>>4;
  u16* zt = zt4[wv];

  // B-frags: nt tiles of 16 cols; element j = w2[(kc*8+j)][nt*16+m]
  bf8v Bf[4];
  #pragma unroll
  for (int nt=0;nt<4;nt++){
    #pragma unroll
    for (int j=0;j<8;j++)
      Bf[nt][j] = (short)f2bf(w2[(kc*8+j)*64 + nt*16 + m]);
  }
  // A-frag: x1 = relu(bn1(y1)) for point p0+m, channels kc*8..+8
  uint4 ra = *(const uint4*)(y1 + (size_t)(p0+m)*32 + kc*8);
  float xv[8]; unpack8(ra, xv);
  bf8v Af;
  #pragma unroll
  for (int j=0;j<8;j++){
    int ch = kc*8+j;
    Af[j] = (short)f2bf(fmaxf(fmaf(xv[j], s1s[ch], t1s[ch]), 0.f));
  }
  // mask of valid rows (bits 0..15 of wave ballot)
  unsigned long long msk = __ballot((l<16) && ((voxflag[p0+l]>>31)!=0));

  f4v acc[4];
  #pragma unroll
  for (int nt=0;nt<4;nt++){
    float bb = b2[nt*16+m];
    acc[nt] = (f4v){bb,bb,bb,bb};
    acc[nt] = __builtin_amdgcn_mfma_f32_16x16x32_bf16(Af, Bf[nt], acc[nt], 0,0,0);
  }
  // route to LDS tile [row][ch], zero masked rows
  #pragma unroll
  for (int nt=0;nt<4;nt++){
    #pragma unroll
    for (int r=0;r<4;r++){
      int row = kc*4+r;
      u16 val = ((msk>>row)&1ull) ? f2bf(acc[nt][r]) : (u16)0;
      zt[row*72 + nt*16+m] = val;
    }
  }
  __syncthreads();
  // bn2 partial stats: lane = channel
  {
    float s=0.f, q=0.f;
    #pragma unroll
    for (int mi=0;mi<16;mi++){ float v = bf2f(zt[mi*72 + l]); s+=v; q=fmaf(v,v,q); }
    atomicAdd(&sS[l], s); atomicAdd(&sQ[l], q);
  }
  // store y2: 4 lanes/point, 32B each, coalesced
  {
    int mm = l>>2, q4 = l&3;
    const uint4* src = (const uint4*)(zt + mm*72 + q4*16);
    uint4 v0 = src[0], v1 = src[1];
    uint4* dy = (uint4*)(y2 + (size_t)(p0+mm)*64 + q4*16);
    dy[0]=v0; dy[1]=v1;
  }
  __syncthreads();
  int rep = blockIdx.x & (REP_-1);
  if (tid < 64) atomicAdd(&partC[rep*128+tid], sS[tid]);
  else if (tid < 128) atomicAdd(&partC[rep*128+tid], sQ[tid-64]);
}

// ---------------- zpassM: MFMA z_sorted = relu(bn2(y2)) @ w3 + b3 ------------
__global__ __launch_bounds__(256) void zpassM(const u16* __restrict__ y2,
    const u32* __restrict__ voxflag, const u32* __restrict__ scanned, const u32* __restrict__ bsum,
    const float* __restrict__ s2, const float* __restrict__ t2,
    const float* __restrict__ w3, const float* __restrict__ b3, u16* __restrict__ z)
{
  __shared__ u16 zt4[4][16*72];
  __shared__ float s2s[64], t2s[64];
  int tid = threadIdx.x;
  if (tid < 64){ s2s[tid]=s2[tid]; t2s[tid]=t2[tid]; }
  __syncthreads();
  int wv = tid>>6, l = tid&63;
  int p0 = blockIdx.x*64 + wv*16;
  int m = l&15, kc = l>>4;
  u16* zt = zt4[wv];

  // B-frags: [nt][kt], element j = w3[(kc*8+j+32*kt)][nt*16+m]
  bf8v Bf[4][2];
  #pragma unroll
  for (int nt=0;nt<4;nt++){
    #pragma unroll
    for (int kt=0;kt<2;kt++){
      #pragma unroll
      for (int j=0;j<8;j++)
        Bf[nt][kt][j] = (short)f2bf(w3[(kc*8+j+32*kt)*64 + nt*16 + m]);
    }
  }
  // A-frags: x2 = relu(bn2(y2)), two K-halves
  uint4 r0 = *(const uint4*)(y2 + (size_t)(p0+m)*64 + kc*8);
  uint4 r1 = *(const uint4*)(y2 + (size_t)(p0+m)*64 + 32 + kc*8);
  float x0[8], x1[8]; unpack8(r0,x0); unpack8(r1,x1);
  bf8v A0, A1;
  #pragma unroll
  for (int j=0;j<8;j++){
    int c0 = kc*8+j, c1 = 32+kc*8+j;
    A0[j] = (short)f2bf(fmaxf(fmaf(x0[j], s2s[c0], t2s[c0]), 0.f));
    A1[j] = (short)f2bf(fmaxf(fmaf(x1[j], s2s[c1], t2s[c1]), 0.f));
  }
  f4v acc[4];
  #pragma unroll
  for (int nt=0;nt<4;nt++){
    float bb = b3[nt*16+m];
    acc[nt] = (f4v){bb,bb,bb,bb};
    acc[nt] = __builtin_amdgcn_mfma_f32_16x16x32_bf16(A0, Bf[nt][0], acc[nt], 0,0,0);
    acc[nt] = __builtin_amdgcn_mfma_f32_16x16x32_bf16(A1, Bf[nt][1], acc[nt], 0,0,0);
  }
  #pragma unroll
  for (int nt=0;nt<4;nt++){
    #pragma unroll
    for (int r=0;r<4;r++)
      zt[(kc*4+r)*72 + nt*16+m] = f2bf(acc[nt][r]);
  }
  __syncthreads();
  // store: 4 lanes/point -> z[slot*64 + q*16 .. +32B]; skip masked
  int mm = l>>2, q4 = l&3;
  u32 vf = voxflag[p0+mm];
  if (vf>>31){
    u32 vox = vf & 0xFFFFFu;
    u32 rank = (vf>>20)&63u;
    u32 slot = scanned[vox] + bsum[vox>>10] + rank;
    const uint4* src = (const uint4*)(zt + mm*72 + q4*16);
    uint4 v0 = src[0], v1 = src[1];
    uint4* dz = (uint4*)(z + (size_t)slot*64 + q4*16);
    dz[0]=v0; dz[1]=v1;
  }
}

// ---------------- poolT: gather-max per voxel -> TRANSPOSED bf16 grid --------
__global__ __launch_bounds__(256) void poolT(
    const u32* __restrict__ scanned, const u32* __restrict__ bsum, const u32* __restrict__ cnt,
    const u16* __restrict__ z, u16* __restrict__ pooledT)
{
  __shared__ u16 lds[32][66];
  int tid = threadIdx.x;
  int g = tid>>3, sub = tid&7;
  int v = blockIdx.x*32 + g;
  u32 n = min(cnt[v],64u);
  u16 r[8];
  if (n==0){
    #pragma unroll
    for (int j=0;j<8;j++) r[j]=0;
  } else {
    u32 st = scanned[v] + bsum[v>>10];
    float m[8];
    #pragma unroll
    for (int j=0;j<8;j++) m[j] = -__builtin_inff();
    for (u32 k=0;k<n;k++){
      uint4 a = *(const uint4*)(z + (size_t)(st+k)*64 + sub*8);
      float x[8]; unpack8(a,x);
      #pragma unroll
      for (int j=0;j<8;j++) m[j]=fmaxf(m[j],x[j]);
    }
    #pragma unroll
    for (int j=0;j<8;j++) r[j]=f2bf(m[j]);
  }
  #pragma unroll
  for (int j=0;j<8;j++) lds[g][sub*8+j] = r[j];
  __syncthreads();
  int c = tid>>2, q = tid&3;
  int v0 = blockIdx.x*32;
  int iy0 = v0 & 511, ix = (v0>>9)&511, b = v0>>18;
  u16 o[8];
  #pragma unroll
  for (int m2=0;m2<8;m2++) o[m2] = lds[q*8+m2][c];
  u16* dst = pooledT + (((size_t)(b*64+c)*512 + ix)*512 + iy0 + q*8);
  *(uint4*)dst = *(uint4*)o;
}

// ---------------- dilate: per-(b,c)-plane streaming 3x3 max ------------------
#define ITILE 32
__global__ __launch_bounds__(256) void dilate(const u16* __restrict__ pooledT, float* __restrict__ out)
{
  __shared__ float sh[2][516];
  int it = blockIdx.x;
  int c  = blockIdx.y;
  int b  = blockIdx.z;
  int tid = threadIdx.x;
  int j0 = tid*2;
  const u16* plane = pooledT + ((size_t)(b*64+c)*512)*512;
  float* oplane = out + ((size_t)(b*64+c)*512)*512;
  const float NINF = -__builtin_inff();
  if (tid==0){ sh[0][0]=NINF; sh[1][0]=NINF; }
  if (tid==255){ sh[0][513]=NINF; sh[1][513]=NINF; }
  int i0 = it*ITILE;

  float a0x,a0y,a1x,a1y,a2x,a2y;
  {
    int r = i0-1;
    if (r<0){ a0x=NINF; a0y=NINF; }
    else { u32 w=*(const u32*)(plane+(size_t)r*512+j0); a0x=bf2f((u16)(w&0xFFFFu)); a0y=bf2f((u16)(w>>16)); }
  }
  {
    u32 w=*(const u32*)(plane+(size_t)i0*512+j0); a1x=bf2f((u16)(w&0xFFFFu)); a1y=bf2f((u16)(w>>16));
  }
  for (int i=i0; i<i0+ITILE; i++){
    int r = i+1;
    if (r>511){ a2x=NINF; a2y=NINF; }
    else { u32 w=*(const u32*)(plane+(size_t)r*512+j0); a2x=bf2f((u16)(w&0xFFFFu)); a2y=bf2f((u16)(w>>16)); }
    int buf = i&1;
    sh[buf][1+j0] = fmaxf(fmaxf(a0x,a1x),a2x);
    sh[buf][2+j0] = fmaxf(fmaxf(a0y,a1y),a2y);
    __syncthreads();
    float s0=sh[buf][j0], s1=sh[buf][j0+1], s2=sh[buf][j0+2], s3=sh[buf][j0+3];
    float2 o = make_float2(fmaxf(fmaxf(s0,s1),s2), fmaxf(fmaxf(s1,s2),s3));
    *(float2*)(oplane + (size_t)i*512 + j0) = o;
    a0x=a1x; a0y=a1y; a1x=a2x; a1y=a2y;
  }
}

// -----------------------------------------------------------------------------
extern "C" void kernel_launch(void* const* d_in, const int* in_sizes, int n_in,
                              void* d_out, int out_size, void* d_ws, size_t ws_size,
                              hipStream_t stream) {
  const float* fea  = (const float*)d_in[0];
  const int*   xy   = (const int*)d_in[1];
  const int*   lab  = (const int*)d_in[2];
  const float* emb  = (const float*)d_in[3];
  const float* bn0g = (const float*)d_in[4];
  const float* bn0b = (const float*)d_in[5];
  const float* w1   = (const float*)d_in[6];
  const float* b1   = (const float*)d_in[7];
  const float* bn1g = (const float*)d_in[8];
  const float* bn1b = (const float*)d_in[9];
  const float* w2   = (const float*)d_in[10];
  const float* b2   = (const float*)d_in[11];
  const float* bn2g = (const float*)d_in[12];
  const float* bn2b = (const float*)d_in[13];
  const float* w3   = (const float*)d_in[14];
  const float* b3   = (const float*)d_in[15];

  char* ws = (char*)d_ws;
  size_t off = 0;
  u16*  z       = (u16*)(ws + off); off += (size_t)P_*64*2;   // 67.1 MB (voxel-sorted)
  u16*  pooledT = (u16*)(ws + off); off += (size_t)S_*64*2;   // 134.2 MB transposed
  u32*  cnt     = (u32*)(ws + off); off += (size_t)S_*4;
  u32*  scanned = (u32*)(ws + off); off += (size_t)S_*4;
  u32*  voxflag = (u32*)(ws + off); off += (size_t)P_*4;
  u32*  blockSum= (u32*)(ws + off); off += 4096;
  float* stats  = (float*)(ws + off);
  float* partA = stats + 0;
  float* partB = stats + 2048;
  float* partC = stats + 4096;
  u32*  cntW = (u32*)(stats + 8192);
  float* c1f = stats + 8256;
  float* s1  = stats + 8288;
  float* t1  = stats + 8320;
  float* s2  = stats + 8352;
  float* t2  = stats + 8416;
  float* W1T = stats + 8480;      // 1024

  u16* y1 = (u16*)d_out;                                  // P*32 bf16
  u16* y2 = (u16*)((char*)d_out + (size_t)P_*32*2);       // P*64 bf16
  float* out = (float*)d_out;

  zeroK<<<S_/1024, 256, 0, stream>>>(cnt, stats);
  passA<<<P_/256, 256, 0, stream>>>(fea, xy, lab, emb, cnt, voxflag, partA);
  scan1<<<S_/1024, 256, 0, stream>>>(cnt, scanned, blockSum);
  scan2p0<<<1, 256, 0, stream>>>(blockSum, cntW, partA, bn0g, bn0b, w1, b1, W1T, c1f);
  passB<<<P_/256, 256, 0, stream>>>(fea, lab, emb, voxflag, W1T, c1f, y1, partB);
  p1k<<<1, 32, 0, stream>>>(partB, cntW, bn1g, bn1b, s1, t1);
  passCM<<<P_/64, 256, 0, stream>>>(y1, voxflag, s1, t1, w2, b2, y2, partC);
  p2k<<<1, 128, 0, stream>>>(partC, cntW, bn2g, bn2b, s2, t2);
  zpassM<<<P_/64, 256, 0, stream>>>(y2, voxflag, scanned, blockSum, s2, t2, w3, b3, z);
  poolT<<<S_/32, 256, 0, stream>>>(scanned, blockSum, cnt, z, pooledT);
  dim3 dg(GX_/ITILE, 64, B_);
  dilate<<<dg, 256, 0, stream>>>(pooledT, out);
}